// Round 10
// baseline (1135.530 us; speedup 1.0000x reference)
//
#include <hip/hip_runtime.h>

#define D 256
#define MAXB 128          // >= ceil(n/1024); supports n <= 131072 (problem: n=100000)
#define SR 1024           // rows per bucket
#define PCH 16384         // edges per partition chunk (588 blocks -> occupancy for latency-bound bpart)

typedef __attribute__((ext_vector_type(8))) short short8;
typedef __attribute__((ext_vector_type(4))) float f32x4;

__device__ __forceinline__ ushort f2b(float f) {
    unsigned u = __float_as_uint(f);
    u += 0x7fffu + ((u >> 16) & 1u);   // round-to-nearest-even
    return (ushort)(u >> 16);
}
__device__ __forceinline__ float b2f(ushort h) {
    return __uint_as_float(((unsigned)h) << 16);
}
__device__ __forceinline__ long long ntload_ll(const void* p) {
    return __builtin_nontemporal_load((const long long*)p);
}

// ---------------- conversions ----------------
__global__ void xconv_kernel(const float* __restrict__ X, ushort* __restrict__ Xb, int total8) {
    int i = blockIdx.x * 256 + threadIdx.x;
    if (i >= total8) return;
    const float4 a = *(const float4*)(X + (size_t)i * 8);
    const float4 b = *(const float4*)(X + (size_t)i * 8 + 4);
    ushort o8[8] = {f2b(a.x), f2b(a.y), f2b(a.z), f2b(a.w),
                    f2b(b.x), f2b(b.y), f2b(b.z), f2b(b.w)};
    *(short8*)(Xb + (size_t)i * 8) = *(const short8*)o8;
}

// WT[h][c][k] = bf16(W[h][k][c])
__global__ void wconv_kernel(const float* __restrict__ W, ushort* __restrict__ WT, int total) {
    int idx = blockIdx.x * 256 + threadIdx.x;
    if (idx >= total) return;
    int h = idx >> 16;
    int c = (idx >> 8) & 255, k = idx & 255;
    WT[(h << 16) + c * 256 + k] = f2b(W[(h << 16) + k * 256 + c]);
}

// ---------------- chunk-major partition: no global atomics, streaming writes ----------------
// Block (c,h) groups its chunk's edges by bucket into raw[h*e + c0 .. c1), and records
// run starts in runofs[(h*nch + c)*(nbuk+1) + b] (absolute into raw); [nbuk] = chunk end.
__global__ __launch_bounds__(512) void bpart_kernel(const int* __restrict__ rows,
                                                    const int* __restrict__ cols,
                                                    const float* __restrict__ vals,
                                                    int2* __restrict__ raw,
                                                    int* __restrict__ runofs,
                                                    int e, int nbuk, int nch) {
    __shared__ int lh[MAXB];    // hist -> absolute write base
    __shared__ int lcur[MAXB];
    int h = blockIdx.y, c = blockIdx.x;
    int c0 = c * PCH, c1 = min(c0 + PCH, e);
    if (c0 >= c1) return;
    const int*   rr = rows + (size_t)h * e;
    const int*   cc = cols + (size_t)h * e;
    const float* vv = vals + (size_t)h * e;
    int tid = threadIdx.x;
    for (int k = tid; k < nbuk; k += 512) { lh[k] = 0; lcur[k] = 0; }
    __syncthreads();
    for (int i = c0 + tid; i < c1; i += 512)
        atomicAdd(&lh[rr[i] >> 10], 1);
    __syncthreads();
    int* ro = runofs + (size_t)(h * nch + c) * (nbuk + 1);
    if (tid == 0) {
        int run = h * e + c0;
        for (int j = 0; j < nbuk; ++j) {
            ro[j] = run;
            int v = lh[j];
            lh[j] = run;      // repurpose as absolute base
            run += v;
        }
        ro[nbuk] = h * e + c1;
    }
    __syncthreads();
    for (int i = c0 + tid; i < c1; i += 512) {
        int row = rr[i];
        int b = row >> 10;
        int p = lh[b] + atomicAdd(&lcur[b], 1);
        raw[p] = make_int2(cc[i] | ((row & 1023) << 17), __float_as_int(vv[i]));
    }
}

// ---------------- scan: per-bucket totals from run table -> gbase (+sentinel), one block ----------------
__global__ __launch_bounds__(1024) void bscan_kernel(const int* __restrict__ runofs,
                                                     int* __restrict__ gbase,
                                                     int nbuk, int nch, int nkeytot) {
    __shared__ int s[1024];
    int t = threadIdx.x;
    int sum = 0;
    if (t < nkeytot) {
        int h = t / nbuk, b = t % nbuk;
        for (int c = 0; c < nch; ++c) {
            const int* ro = runofs + (size_t)(h * nch + c) * (nbuk + 1) + b;
            sum += ro[1] - ro[0];
        }
    }
    s[t] = sum;
    __syncthreads();
    for (int off = 1; off < 1024; off <<= 1) {
        int x = (t >= off) ? s[t - off] : 0;
        __syncthreads();
        s[t] += x;
        __syncthreads();
    }
    if (t < nkeytot) gbase[t] = s[t] - sum;   // exclusive
    if (t == nkeytot - 1) gbase[nkeytot] = s[t];
}

// ---------------- per-bucket exact sort: wave-per-fragment reads -> eg + exact row_ptr ----------------
__global__ __launch_bounds__(512) void bsort_kernel(const int* __restrict__ gbase,
                                                    const int* __restrict__ runofs,
                                                    const int2* __restrict__ raw,
                                                    int2* __restrict__ eg,
                                                    int* __restrict__ row_ptr,
                                                    int n, int nbuk, int nch) {
    __shared__ int hist[1024];
    __shared__ int ss[512];
    __shared__ int cur[1024];
    int key = blockIdx.x;            // 0 .. hops*nbuk-1
    int h = key / nbuk, b = key % nbuk;
    int s = gbase[key], t = gbase[key + 1];
    int tid = threadIdx.x;
    int w = tid >> 6, lane = tid & 63;   // 8 waves
    hist[tid] = 0; hist[tid + 512] = 0;
    __syncthreads();
    // hist pass: wave w owns fragments w, w+8, ...
    for (int c = w; c < nch; c += 8) {
        const int* ro = runofs + (size_t)(h * nch + c) * (nbuk + 1) + b;
        int rs = ro[0], re = ro[1];
        for (int i = rs + lane; i < re; i += 64)
            atomicAdd(&hist[(((unsigned)raw[i].x) >> 17) & 1023], 1);
    }
    __syncthreads();
    int a = hist[2 * tid], c2 = hist[2 * tid + 1];
    int pair = a + c2;
    ss[tid] = pair;
    __syncthreads();
    for (int off = 1; off < 512; off <<= 1) {
        int x = (tid >= off) ? ss[tid - off] : 0;
        __syncthreads();
        ss[tid] += x;
        __syncthreads();
    }
    int excl = s + ss[tid] - pair;   // absolute start of row 2*tid in this bucket
    cur[2 * tid] = excl;
    cur[2 * tid + 1] = excl + a;
    int* rp = row_ptr + (size_t)h * (n + 1);
    int grow = b * SR + 2 * tid;
    if (grow < n)     rp[grow]     = excl;
    if (grow + 1 < n) rp[grow + 1] = excl + a;
    if (tid == 0 && b == nbuk - 1) rp[n] = t;
    __syncthreads();
    // scatter pass: same wave-per-fragment mapping
    for (int c = w; c < nch; c += 8) {
        const int* ro = runofs + (size_t)(h * nch + c) * (nbuk + 1) + b;
        int rs = ro[0], re = ro[1];
        for (int i = rs + lane; i < re; i += 64) {
            int2 ev = raw[i];
            int j = (((unsigned)ev.x) >> 17) & 1023;
            int p = atomicAdd(&cur[j], 1);
            eg[p] = ev;   // row bits kept; spmm masks them off
        }
    }
}

// ---------------- SpMM: one wave per row, quarter-wave per edge, pipelined gathers ----------------
// blockIdx.y = hop (rpStride/yStride select the hop's CSR and Y slice)
__global__ __launch_bounds__(256) void spmmX_kernel(const int* __restrict__ row_ptr,
                                                    const int2* __restrict__ eg,
                                                    const ushort* __restrict__ Xb,
                                                    ushort* __restrict__ Y, int n,
                                                    size_t rpStride, size_t yStride) {
    const int* rp = row_ptr + blockIdx.y * rpStride;
    ushort* Yh = Y + blockIdx.y * yStride;
    int w = threadIdx.x >> 6, lane = threadIdx.x & 63;
    int r = blockIdx.x * 4 + w;
    if (r >= n) return;
    int g = lane >> 4, l4 = lane & 15;
    int doff = l4 * 16;               // 16 cols (32B) per lane
    const ushort* xb = Xb + doff;
    int e0 = rp[r], e1 = rp[r + 1];
    float acc[16] = {};

    int i0 = e0 + g;
    long long d_cur = (i0 < e1) ? ntload_ll(eg + i0) : 0;
    int c_cur = ((int)(unsigned)d_cur) & 0x1FFFF;
    short8 va = *(const short8*)(xb + (size_t)c_cur * 256);
    short8 vb = *(const short8*)(xb + (size_t)c_cur * 256 + 8);
    int i1 = e0 + 4 + g;
    long long d_nxt = (i1 < e1) ? ntload_ll(eg + i1) : 0;

    for (int ee = e0; ee < e1; ee += 4) {
        int c_nxt = ((int)(unsigned)d_nxt) & 0x1FFFF;
        short8 wa = *(const short8*)(xb + (size_t)c_nxt * 256);
        short8 wb = *(const short8*)(xb + (size_t)c_nxt * 256 + 8);
        int i2 = ee + 8 + g;
        long long d_n2 = (i2 < e1) ? ntload_ll(eg + i2) : 0;

        float val = __int_as_float((int)(d_cur >> 32));
        #pragma unroll
        for (int i = 0; i < 8; ++i)
            acc[i] = fmaf(val, b2f((ushort)va[i]), acc[i]);
        #pragma unroll
        for (int i = 0; i < 8; ++i)
            acc[8 + i] = fmaf(val, b2f((ushort)vb[i]), acc[8 + i]);

        d_cur = d_nxt; va = wa; vb = wb; d_nxt = d_n2;
    }
    #pragma unroll
    for (int i = 0; i < 16; ++i) acc[i] += __shfl_xor(acc[i], 16);
    #pragma unroll
    for (int i = 0; i < 16; ++i) acc[i] += __shfl_xor(acc[i], 32);
    if (g == 0) {
        union { ushort u[16]; long long ll[4]; } o;
        #pragma unroll
        for (int i = 0; i < 16; ++i) o.u[i] = f2b(acc[i]);
        long long* dst = (long long*)(Yh + (size_t)r * 256 + doff);
        __builtin_nontemporal_store(o.ll[0], dst);
        __builtin_nontemporal_store(o.ll[1], dst + 1);
        __builtin_nontemporal_store(o.ll[2], dst + 2);
        __builtin_nontemporal_store(o.ll[3], dst + 3);
    }
}

// ---------------- GEMM: 64-row x 256-col tile, K = nh*256 fused; Y read exactly once ----------------
#define BP 40   // Bs/As leading dim (bf16 elems), 80B rows keep 16B alignment

__global__ __launch_bounds__(256) void gemmY2_kernel(const ushort* __restrict__ Y,
                                                     const ushort* __restrict__ WT,
                                                     float* __restrict__ out, int M,
                                                     int nh, int hoff, int mode) {
    __shared__ ushort As[64 * BP];     //  5.1 KB
    __shared__ ushort Bs[256 * BP];    // 20.5 KB
    int tid = threadIdx.x;
    int r0 = blockIdx.x * 64;
    int w = tid >> 6, lane = tid & 63;
    int lo = lane & 15, hi = lane >> 4;
    f32x4 acc[16] = {};

    int srow = tid >> 2;            // 0..63
    int skq = (tid & 3) * 8;        // 0,8,16,24
    int arow = r0 + srow; if (arow > M - 1) arow = M - 1;

    for (int ks = 0; ks < nh * 8; ++ks) {
        int hh = ks >> 3, k0 = (ks & 7) * 32;
        short8 av = *(const short8*)(Y + ((size_t)hh * M + arow) * 256 + k0 + skq);
        const ushort* bp = WT + ((size_t)(hoff + hh) << 16) + (size_t)tid * 256 + k0;
        short8 bv0 = *(const short8*)(bp);
        short8 bv1 = *(const short8*)(bp + 8);
        short8 bv2 = *(const short8*)(bp + 16);
        short8 bv3 = *(const short8*)(bp + 24);
        __syncthreads();
        *(short8*)&As[srow * BP + skq] = av;
        *(short8*)&Bs[tid * BP +  0] = bv0;
        *(short8*)&Bs[tid * BP +  8] = bv1;
        *(short8*)&Bs[tid * BP + 16] = bv2;
        *(short8*)&Bs[tid * BP + 24] = bv3;
        __syncthreads();
        short8 a = *(const short8*)&As[(w * 16 + lo) * BP + hi * 8];
        #pragma unroll
        for (int j = 0; j < 16; ++j) {
            short8 bf = *(const short8*)&Bs[(j * 16 + lo) * BP + hi * 8];
            acc[j] = __builtin_amdgcn_mfma_f32_16x16x32_bf16(a, bf, acc[j], 0, 0, 0);
        }
    }
    // C/D layout (HW-verified): col = lane&15, row = (lane>>4)*4 + reg
    #pragma unroll
    for (int j = 0; j < 16; ++j)
        #pragma unroll
        for (int i = 0; i < 4; ++i) {
            int row = r0 + w * 16 + hi * 4 + i;
            int col = j * 16 + lo;
            if (row < M) {
                float v = acc[j][i];
                float* op = &out[(size_t)row * 256 + col];
                if (mode & 1) v += *op;
                if (mode & 2) v = fmaxf(v, 0.f);
                *op = v;
            }
        }
}

extern "C" void kernel_launch(void* const* d_in, const int* in_sizes, int n_in,
                              void* d_out, int out_size, void* d_ws, size_t ws_size,
                              hipStream_t stream) {
    const float* X    = (const float*)d_in[0];
    const float* W    = (const float*)d_in[1];
    const float* vals = (const float*)d_in[2];
    const int*   rows = (const int*)d_in[3];
    const int*   cols = (const int*)d_in[4];
    int n    = in_sizes[0] / D;         // 100000
    int hops = in_sizes[1] / (D * D);   // 3
    int e    = in_sizes[2] / hops;      // 3200000

    int nbuk    = (n + SR - 1) / SR;    // 98 (<= MAXB)
    int nkeytot = hops * nbuk;          // 294 (<= 1024 for bscan)
    int nch     = (e + PCH - 1) / PCH;  // 196

    float* out = (float*)d_out;

    auto padded = [](size_t b) { return (b + 255) & ~(size_t)255; };
    char* wsb = (char*)d_ws;
    size_t off = 0;
    auto alloc = [&](size_t bytes) -> void* { void* p = wsb + off; off += padded(bytes); return p; };

    // raw is LAST so Y (=hops*n*D*2 bytes) can overlay it and extend into the ws tail
    ushort* WT      = (ushort*)alloc((size_t)hops * D * D * 2);               //  0.4 MB
    ushort* Xb      = (ushort*)alloc((size_t)n * D * 2);                      // 51.2 MB
    int*    runofs  = (int*)   alloc((size_t)hops * nch * (nbuk + 1) * 4);    //  0.23 MB
    int*    gbase   = (int*)   alloc((size_t)(nkeytot + 1) * 4);
    int*    row_ptr = (int*)   alloc((size_t)hops * (n + 1) * 4);             //  1.2 MB
    int2*   edges   = (int2*)  alloc((size_t)hops * e * 8);                   // 76.8 MB
    size_t  raw_off = off;
    int2*   raw     = (int2*)  alloc((size_t)hops * e * 8);                   // 76.8 MB (dead after bsort)

    bool bigY = (ws_size >= raw_off + (size_t)hops * n * D * 2);
    ushort* Y = (ushort*)raw;   // fused: [hops][n][D] over raw+tail; else per-hop [n][D]

    // conversions (independent of partition)
    xconv_kernel<<<(n * D / 8 + 255) / 256, 256, 0, stream>>>(X, Xb, n * D / 8);
    wconv_kernel<<<(hops * D * D + 255) / 256, 256, 0, stream>>>(W, WT, hops * D * D);

    // chunk-major partition (streaming writes, no global atomics) -> run table -> exact CSR
    bpart_kernel<<<dim3(nch, hops), 512, 0, stream>>>(rows, cols, vals, raw, runofs, e, nbuk, nch);
    bscan_kernel<<<1, 1024, 0, stream>>>(runofs, gbase, nbuk, nch, nkeytot);
    bsort_kernel<<<nkeytot, 512, 0, stream>>>(gbase, runofs, raw, edges, row_ptr, n, nbuk, nch);

    if (bigY) {
        spmmX_kernel<<<dim3((n + 3) / 4, hops), 256, 0, stream>>>(row_ptr, edges, Xb, Y, n,
                                                                  (size_t)(n + 1), (size_t)n * D);
        gemmY2_kernel<<<(n + 63) / 64, 256, 0, stream>>>(Y, WT, out, n, hops, 0, 2);
    } else {
        for (int h = 0; h < hops; ++h) {
            spmmX_kernel<<<dim3((n + 3) / 4, 1), 256, 0, stream>>>(row_ptr + (size_t)h * (n + 1),
                                                                   edges, Xb, Y, n, 0, 0);
            int mode = (h > 0 ? 1 : 0) | (h == hops - 1 ? 2 : 0);
            gemmY2_kernel<<<(n + 63) / 64, 256, 0, stream>>>(Y, WT, out, n, 1, h, mode);
        }
    }
}

// Round 11
// 1128.224 us; speedup vs baseline: 1.0065x; 1.0065x over previous
//
#include <hip/hip_runtime.h>

#define D 256
#define MAXB 128          // >= ceil(n/1024); supports n <= 131072 (problem: n=100000)
#define SR 1024           // rows per bucket
#define PCH 16384         // edges per partition chunk

typedef __attribute__((ext_vector_type(8))) short short8;
typedef __attribute__((ext_vector_type(4))) float f32x4;

__device__ __forceinline__ ushort f2b(float f) {
    unsigned u = __float_as_uint(f);
    u += 0x7fffu + ((u >> 16) & 1u);   // round-to-nearest-even
    return (ushort)(u >> 16);
}
__device__ __forceinline__ float b2f(ushort h) {
    return __uint_as_float(((unsigned)h) << 16);
}
__device__ __forceinline__ long long ntload_ll(const void* p) {
    return __builtin_nontemporal_load((const long long*)p);
}

// ---------------- conversions ----------------
__global__ void xconv_kernel(const float* __restrict__ X, ushort* __restrict__ Xb, int total8) {
    int i = blockIdx.x * 256 + threadIdx.x;
    if (i >= total8) return;
    const float4 a = *(const float4*)(X + (size_t)i * 8);
    const float4 b = *(const float4*)(X + (size_t)i * 8 + 4);
    ushort o8[8] = {f2b(a.x), f2b(a.y), f2b(a.z), f2b(a.w),
                    f2b(b.x), f2b(b.y), f2b(b.z), f2b(b.w)};
    *(short8*)(Xb + (size_t)i * 8) = *(const short8*)o8;
}

// WT[h][c][k] = bf16(W[h][k][c])
__global__ void wconv_kernel(const float* __restrict__ W, ushort* __restrict__ WT, int total) {
    int idx = blockIdx.x * 256 + threadIdx.x;
    if (idx >= total) return;
    int h = idx >> 16;
    int c = (idx >> 8) & 255, k = idx & 255;
    WT[(h << 16) + c * 256 + k] = f2b(W[(h << 16) + k * 256 + c]);
}

// ---------------- chunk-major partition: no global atomics, streaming writes ----------------
__global__ __launch_bounds__(512) void bpart_kernel(const int* __restrict__ rows,
                                                    const int* __restrict__ cols,
                                                    const float* __restrict__ vals,
                                                    int2* __restrict__ raw,
                                                    int* __restrict__ runofs,
                                                    int e, int nbuk, int nch) {
    __shared__ int lh[MAXB];    // hist -> absolute write base
    __shared__ int lcur[MAXB];
    int h = blockIdx.y, c = blockIdx.x;
    int c0 = c * PCH, c1 = min(c0 + PCH, e);
    if (c0 >= c1) return;
    const int*   rr = rows + (size_t)h * e;
    const int*   cc = cols + (size_t)h * e;
    const float* vv = vals + (size_t)h * e;
    int tid = threadIdx.x;
    for (int k = tid; k < nbuk; k += 512) { lh[k] = 0; lcur[k] = 0; }
    __syncthreads();
    for (int i = c0 + tid; i < c1; i += 512)
        atomicAdd(&lh[rr[i] >> 10], 1);
    __syncthreads();
    int* ro = runofs + (size_t)(h * nch + c) * (nbuk + 1);
    if (tid == 0) {
        int run = h * e + c0;
        for (int j = 0; j < nbuk; ++j) {
            ro[j] = run;
            int v = lh[j];
            lh[j] = run;      // repurpose as absolute base
            run += v;
        }
        ro[nbuk] = h * e + c1;
    }
    __syncthreads();
    for (int i = c0 + tid; i < c1; i += 512) {
        int row = rr[i];
        int b = row >> 10;
        int p = lh[b] + atomicAdd(&lcur[b], 1);
        raw[p] = make_int2(cc[i] | ((row & 1023) << 17), __float_as_int(vv[i]));
    }
}

// ---------------- scan: per-bucket totals from run table -> gbase (+sentinel), one block ----------------
__global__ __launch_bounds__(1024) void bscan_kernel(const int* __restrict__ runofs,
                                                     int* __restrict__ gbase,
                                                     int nbuk, int nch, int nkeytot) {
    __shared__ int s[1024];
    int t = threadIdx.x;
    int sum = 0;
    if (t < nkeytot) {
        int h = t / nbuk, b = t % nbuk;
        for (int c = 0; c < nch; ++c) {
            const int* ro = runofs + (size_t)(h * nch + c) * (nbuk + 1) + b;
            sum += ro[1] - ro[0];
        }
    }
    s[t] = sum;
    __syncthreads();
    for (int off = 1; off < 1024; off <<= 1) {
        int x = (t >= off) ? s[t - off] : 0;
        __syncthreads();
        s[t] += x;
        __syncthreads();
    }
    if (t < nkeytot) gbase[t] = s[t] - sum;   // exclusive
    if (t == nkeytot - 1) gbase[nkeytot] = s[t];
}

// ---------------- per-bucket exact sort: wave-per-fragment reads -> eg + exact row_ptr ----------------
__global__ __launch_bounds__(512) void bsort_kernel(const int* __restrict__ gbase,
                                                    const int* __restrict__ runofs,
                                                    const int2* __restrict__ raw,
                                                    int2* __restrict__ eg,
                                                    int* __restrict__ row_ptr,
                                                    int n, int nbuk, int nch) {
    __shared__ int hist[1024];
    __shared__ int ss[512];
    __shared__ int cur[1024];
    int key = blockIdx.x;            // 0 .. hops*nbuk-1
    int h = key / nbuk, b = key % nbuk;
    int s = gbase[key], t = gbase[key + 1];
    int tid = threadIdx.x;
    int w = tid >> 6, lane = tid & 63;   // 8 waves
    hist[tid] = 0; hist[tid + 512] = 0;
    __syncthreads();
    for (int c = w; c < nch; c += 8) {
        const int* ro = runofs + (size_t)(h * nch + c) * (nbuk + 1) + b;
        int rs = ro[0], re = ro[1];
        for (int i = rs + lane; i < re; i += 64)
            atomicAdd(&hist[(((unsigned)raw[i].x) >> 17) & 1023], 1);
    }
    __syncthreads();
    int a = hist[2 * tid], c2 = hist[2 * tid + 1];
    int pair = a + c2;
    ss[tid] = pair;
    __syncthreads();
    for (int off = 1; off < 512; off <<= 1) {
        int x = (tid >= off) ? ss[tid - off] : 0;
        __syncthreads();
        ss[tid] += x;
        __syncthreads();
    }
    int excl = s + ss[tid] - pair;   // absolute start of row 2*tid in this bucket
    cur[2 * tid] = excl;
    cur[2 * tid + 1] = excl + a;
    int* rp = row_ptr + (size_t)h * (n + 1);
    int grow = b * SR + 2 * tid;
    if (grow < n)     rp[grow]     = excl;
    if (grow + 1 < n) rp[grow + 1] = excl + a;
    if (tid == 0 && b == nbuk - 1) rp[n] = t;
    __syncthreads();
    for (int c = w; c < nch; c += 8) {
        const int* ro = runofs + (size_t)(h * nch + c) * (nbuk + 1) + b;
        int rs = ro[0], re = ro[1];
        for (int i = rs + lane; i < re; i += 64) {
            int2 ev = raw[i];
            int j = (((unsigned)ev.x) >> 17) & 1023;
            int p = atomicAdd(&cur[j], 1);
            eg[p] = ev;   // row bits kept; spmm masks them off
        }
    }
}

// ---------------- SpMM (half-D): one wave per row, quarter-wave per edge ----------------
// Dispatch computes Y[:, half*128 .. +128): per-dispatch gather footprint = 25.6MB of
// distinct 64B lines (<= effective L2 ~27MB) -> L2-resident random gather.
__global__ __launch_bounds__(256) void spmmX_kernel(const int* __restrict__ row_ptr,
                                                    const int2* __restrict__ eg,
                                                    const ushort* __restrict__ Xb,
                                                    ushort* __restrict__ Y, int n,
                                                    size_t rpStride, size_t yStride, int half) {
    const int* rp = row_ptr + blockIdx.y * rpStride;
    ushort* Yh = Y + blockIdx.y * yStride;
    int w = threadIdx.x >> 6, lane = threadIdx.x & 63;
    int r = blockIdx.x * 4 + w;
    if (r >= n) return;
    int g = lane >> 4, l4 = lane & 15;
    int doff = half * 128 + l4 * 8;   // 8 cols (16B) per lane, 16 lanes = 128 cols
    const ushort* xb = Xb + doff;
    int e0 = rp[r], e1 = rp[r + 1];
    float acc[8] = {};

    int i0 = e0 + g;
    long long d_cur = (i0 < e1) ? ntload_ll(eg + i0) : 0;
    int c_cur = ((int)(unsigned)d_cur) & 0x1FFFF;
    short8 va = *(const short8*)(xb + (size_t)c_cur * 256);
    int i1 = e0 + 4 + g;
    long long d_nxt = (i1 < e1) ? ntload_ll(eg + i1) : 0;

    for (int ee = e0; ee < e1; ee += 4) {
        int c_nxt = ((int)(unsigned)d_nxt) & 0x1FFFF;
        short8 wa = *(const short8*)(xb + (size_t)c_nxt * 256);
        int i2 = ee + 8 + g;
        long long d_n2 = (i2 < e1) ? ntload_ll(eg + i2) : 0;

        float val = __int_as_float((int)(d_cur >> 32));
        #pragma unroll
        for (int i = 0; i < 8; ++i)
            acc[i] = fmaf(val, b2f((ushort)va[i]), acc[i]);

        d_cur = d_nxt; va = wa; d_nxt = d_n2;
    }
    #pragma unroll
    for (int i = 0; i < 8; ++i) acc[i] += __shfl_xor(acc[i], 16);
    #pragma unroll
    for (int i = 0; i < 8; ++i) acc[i] += __shfl_xor(acc[i], 32);
    if (g == 0) {
        union { ushort u[8]; long long ll[2]; } o;
        #pragma unroll
        for (int i = 0; i < 8; ++i) o.u[i] = f2b(acc[i]);
        long long* dst = (long long*)(Yh + (size_t)r * 256 + doff);
        __builtin_nontemporal_store(o.ll[0], dst);
        __builtin_nontemporal_store(o.ll[1], dst + 1);
    }
}

// ---------------- GEMM: 64-row x 256-col tile, K = nh*256 fused; Y read exactly once ----------------
#define BP 40   // Bs/As leading dim (bf16 elems), 80B rows keep 16B alignment

__global__ __launch_bounds__(256) void gemmY2_kernel(const ushort* __restrict__ Y,
                                                     const ushort* __restrict__ WT,
                                                     float* __restrict__ out, int M,
                                                     int nh, int hoff, int mode) {
    __shared__ ushort As[64 * BP];     //  5.1 KB
    __shared__ ushort Bs[256 * BP];    // 20.5 KB
    int tid = threadIdx.x;
    int r0 = blockIdx.x * 64;
    int w = tid >> 6, lane = tid & 63;
    int lo = lane & 15, hi = lane >> 4;
    f32x4 acc[16] = {};

    int srow = tid >> 2;            // 0..63
    int skq = (tid & 3) * 8;        // 0,8,16,24
    int arow = r0 + srow; if (arow > M - 1) arow = M - 1;

    for (int ks = 0; ks < nh * 8; ++ks) {
        int hh = ks >> 3, k0 = (ks & 7) * 32;
        short8 av = *(const short8*)(Y + ((size_t)hh * M + arow) * 256 + k0 + skq);
        const ushort* bp = WT + ((size_t)(hoff + hh) << 16) + (size_t)tid * 256 + k0;
        short8 bv0 = *(const short8*)(bp);
        short8 bv1 = *(const short8*)(bp + 8);
        short8 bv2 = *(const short8*)(bp + 16);
        short8 bv3 = *(const short8*)(bp + 24);
        __syncthreads();
        *(short8*)&As[srow * BP + skq] = av;
        *(short8*)&Bs[tid * BP +  0] = bv0;
        *(short8*)&Bs[tid * BP +  8] = bv1;
        *(short8*)&Bs[tid * BP + 16] = bv2;
        *(short8*)&Bs[tid * BP + 24] = bv3;
        __syncthreads();
        short8 a = *(const short8*)&As[(w * 16 + lo) * BP + hi * 8];
        #pragma unroll
        for (int j = 0; j < 16; ++j) {
            short8 bf = *(const short8*)&Bs[(j * 16 + lo) * BP + hi * 8];
            acc[j] = __builtin_amdgcn_mfma_f32_16x16x32_bf16(a, bf, acc[j], 0, 0, 0);
        }
    }
    // C/D layout (HW-verified): col = lane&15, row = (lane>>4)*4 + reg
    #pragma unroll
    for (int j = 0; j < 16; ++j)
        #pragma unroll
        for (int i = 0; i < 4; ++i) {
            int row = r0 + w * 16 + hi * 4 + i;
            int col = j * 16 + lo;
            if (row < M) {
                float v = acc[j][i];
                float* op = &out[(size_t)row * 256 + col];
                if (mode & 1) v += *op;
                if (mode & 2) v = fmaxf(v, 0.f);
                *op = v;
            }
        }
}

extern "C" void kernel_launch(void* const* d_in, const int* in_sizes, int n_in,
                              void* d_out, int out_size, void* d_ws, size_t ws_size,
                              hipStream_t stream) {
    const float* X    = (const float*)d_in[0];
    const float* W    = (const float*)d_in[1];
    const float* vals = (const float*)d_in[2];
    const int*   rows = (const int*)d_in[3];
    const int*   cols = (const int*)d_in[4];
    int n    = in_sizes[0] / D;         // 100000
    int hops = in_sizes[1] / (D * D);   // 3
    int e    = in_sizes[2] / hops;      // 3200000

    int nbuk    = (n + SR - 1) / SR;    // 98 (<= MAXB)
    int nkeytot = hops * nbuk;          // 294 (<= 1024 for bscan)
    int nch     = (e + PCH - 1) / PCH;  // 196

    float* out = (float*)d_out;

    auto padded = [](size_t b) { return (b + 255) & ~(size_t)255; };
    char* wsb = (char*)d_ws;
    size_t off = 0;
    auto alloc = [&](size_t bytes) -> void* { void* p = wsb + off; off += padded(bytes); return p; };

    // raw is LAST so Y (=hops*n*D*2 bytes) can overlay it and extend into the ws tail
    ushort* WT      = (ushort*)alloc((size_t)hops * D * D * 2);               //  0.4 MB
    ushort* Xb      = (ushort*)alloc((size_t)n * D * 2);                      // 51.2 MB
    int*    runofs  = (int*)   alloc((size_t)hops * nch * (nbuk + 1) * 4);    //  0.23 MB
    int*    gbase   = (int*)   alloc((size_t)(nkeytot + 1) * 4);
    int*    row_ptr = (int*)   alloc((size_t)hops * (n + 1) * 4);             //  1.2 MB
    int2*   edges   = (int2*)  alloc((size_t)hops * e * 8);                   // 76.8 MB
    size_t  raw_off = off;
    int2*   raw     = (int2*)  alloc((size_t)hops * e * 8);                   // 76.8 MB (dead after bsort)

    bool bigY = (ws_size >= raw_off + (size_t)hops * n * D * 2);
    ushort* Y = (ushort*)raw;   // fused: [hops][n][D] over raw+tail; else per-hop [n][D]

    // conversions (independent of partition)
    xconv_kernel<<<(n * D / 8 + 255) / 256, 256, 0, stream>>>(X, Xb, n * D / 8);
    wconv_kernel<<<(hops * D * D + 255) / 256, 256, 0, stream>>>(W, WT, hops * D * D);

    // chunk-major partition (streaming writes, no global atomics) -> run table -> exact CSR
    bpart_kernel<<<dim3(nch, hops), 512, 0, stream>>>(rows, cols, vals, raw, runofs, e, nbuk, nch);
    bscan_kernel<<<1, 1024, 0, stream>>>(runofs, gbase, nbuk, nch, nkeytot);
    bsort_kernel<<<nkeytot, 512, 0, stream>>>(gbase, runofs, raw, edges, row_ptr, n, nbuk, nch);

    if (bigY) {
        // two sequential half-D SpMM dispatches: each has a 25.6MB gather footprint
        for (int s = 0; s < 2; ++s)
            spmmX_kernel<<<dim3((n + 3) / 4, hops), 256, 0, stream>>>(row_ptr, edges, Xb, Y, n,
                                                                      (size_t)(n + 1),
                                                                      (size_t)n * D, s);
        gemmY2_kernel<<<(n + 63) / 64, 256, 0, stream>>>(Y, WT, out, n, hops, 0, 2);
    } else {
        for (int h = 0; h < hops; ++h) {
            for (int s = 0; s < 2; ++s)
                spmmX_kernel<<<dim3((n + 3) / 4, 1), 256, 0, stream>>>(row_ptr + (size_t)h * (n + 1),
                                                                       edges, Xb, Y, n, 0, 0, s);
            int mode = (h > 0 ? 1 : 0) | (h == hops - 1 ? 2 : 0);
            gemmY2_kernel<<<(n + 63) / 64, 256, 0, stream>>>(Y, WT, out, n, 1, h, mode);
        }
    }
}